// Round 14
// baseline (82.557 us; speedup 1.0000x reference)
//
#include <hip/hip_runtime.h>
#include <math.h>

#define NLAT 360
#define NLON 720
#define LMAX 360
#define MMAX 361
#define KPADC 384   // stage-1 cols per bc: 192 kf x 2 (s)
#define KFP  192    // folded-k padded length (180 data + 12 zero pad)
#define FT_COLS 736
#define FT_ROWS_PAD 384
#define NJ   32
#define XST  744

typedef __attribute__((ext_vector_type(4))) float f32x4;
typedef __attribute__((ext_vector_type(8))) short bf16x8;
typedef __attribute__((ext_vector_type(4))) short bf16x4;

__device__ __forceinline__ short f2bf(float f) {
    union { float f; unsigned u; } v; v.f = f;
    unsigned r = (v.u + 0x7FFFu + ((v.u >> 16) & 1u)) >> 16;
    return (short)r;
}

// ------- kernel 0: bf16 cosine-DFT matrix FT[m][n], pads written as 0 ------
__global__ __launch_bounds__(256) void fill_ft_kernel(short* __restrict__ FT) {
    int idx = blockIdx.x * 256 + threadIdx.x;
    const int total = FT_ROWS_PAD * FT_COLS;
    if (idx >= total) return;
    int n = idx % FT_COLS;
    int m = idx / FT_COLS;
    short val = 0;
    if (m < MMAX && n < NLON) {
        int t = (m * n) % NLON;
        float s, c;
        sincospif((float)t / 360.0f, &s, &c);
        val = f2bf((6.283185307179586f / 720.0f) * c);
    }
    FT[idx] = val;
}

// ---------------- stage 1: x-panel DFT + parity fold (validated r12/r13) ---
__global__ __launch_bounds__(512) void stage1_kernel(const float* __restrict__ x,
                                                     const short* __restrict__ FT,
                                                     short* __restrict__ EO,
                                                     int m0, int cm) {
    __shared__ __align__(16) short Xs[64][XST];
    const int tid  = threadIdx.x;
    const int wav  = tid >> 6;
    const int lane = tid & 63;
    const int col0 = blockIdx.x * 64;
    const int m_hi = (m0 + cm < MMAX) ? (m0 + cm) : MMAX;

    for (int p = tid; p < 64 * 92; p += 512) {
        const int row = p / 92;
        const int c   = p - row * 92;
        const int gb  = col0 + row;
        const int bc  = gb / KPADC;
        const int q   = gb - bc * KPADC;
        const int kf  = q >> 1;
        const int s   = q & 1;
        const int klat = s ? (NLAT - 1 - kf) : kf;
        f32x4 va = {0,0,0,0}, vb = {0,0,0,0};
        if (c < 90 && kf < 180) {
            const float* xp = x + ((size_t)bc * NLAT + klat) * NLON + c * 8;
            va = *(const f32x4*)xp;
            vb = *(const f32x4*)(xp + 4);
        }
        bf16x8 wv;
        #pragma unroll
        for (int e = 0; e < 4; ++e) { wv[e] = f2bf(va[e]); wv[e + 4] = f2bf(vb[e]); }
        *(bf16x8*)&Xs[row][c * 8] = wv;
    }
    __syncthreads();

    const int r    = lane & 15;
    const int kg   = (lane >> 4) * 8;
    const int rowg = (lane >> 4) * 4;

    for (int mb = m0; mb < m_hi; mb += 256) {
        const int mwb = mb + wav * 32;
        if (mwb >= m_hi) continue;
        int mA0 = mwb + r;      if (mA0 > FT_ROWS_PAD - 1) mA0 = FT_ROWS_PAD - 1;
        int mA1 = mwb + 16 + r; if (mA1 > FT_ROWS_PAD - 1) mA1 = FT_ROWS_PAD - 1;
        const short* ap0 = FT + (size_t)mA0 * FT_COLS + kg;
        const short* ap1 = FT + (size_t)mA1 * FT_COLS + kg;

        f32x4 acc0[4] = {{0,0,0,0},{0,0,0,0},{0,0,0,0},{0,0,0,0}};
        f32x4 acc1[4] = {{0,0,0,0},{0,0,0,0},{0,0,0,0},{0,0,0,0}};

        bf16x8 A0c = *(const bf16x8*)ap0;
        bf16x8 A1c = *(const bf16x8*)ap1;
        #pragma unroll
        for (int t = 0; t < 23; ++t) {
            bf16x8 A0n, A1n;
            if (t < 22) {
                A0n = *(const bf16x8*)(ap0 + (t + 1) * 32);
                A1n = *(const bf16x8*)(ap1 + (t + 1) * 32);
            }
            #pragma unroll
            for (int f = 0; f < 4; ++f) {
                bf16x8 bfr = *(const bf16x8*)&Xs[f * 16 + r][t * 32 + kg];
                acc0[f] = __builtin_amdgcn_mfma_f32_16x16x32_bf16(A0c, bfr, acc0[f], 0, 0, 0);
                acc1[f] = __builtin_amdgcn_mfma_f32_16x16x32_bf16(A1c, bfr, acc1[f], 0, 0, 0);
            }
            A0c = A0n; A1c = A1n;
        }

        #pragma unroll
        for (int f = 0; f < 4; ++f) {
            const int col = col0 + f * 16 + r;
            const int bc  = col / KPADC;
            const int q   = col - bc * KPADC;
            const int kf  = q >> 1;
            const int e   = q & 1;
            #pragma unroll
            for (int i = 0; i < 4; ++i) {
                const int ma = mwb + rowg + i;
                const int mc = ma + 16;
                float v0 = acc0[f][i];
                float p0 = __shfl_xor(v0, 1);
                float val0 = e ? (p0 - v0) : (v0 + p0);
                float v1 = acc1[f][i];
                float p1 = __shfl_xor(v1, 1);
                float val1 = e ? (p1 - v1) : (v1 + p1);
                if (ma < m_hi)
                    EO[(((size_t)(ma - m0) * 2 + e) * NJ + bc) * KFP + kf] = f2bf(val0);
                if (mc < m_hi)
                    EO[(((size_t)(mc - m0) * 2 + e) * NJ + bc) * KFP + kf] = f2bf(val1);
            }
        }
    }
}

// ---------------- stage 2: barrier-minimal 1-m blocks, parity fold ---------
// Block 128 thr = 2 waves (bc halves); tile 1m x 32l x 32bc; K = 6x32 folded.
// W[m][l0..l0+32][0..192) staged coalesced -> LDS [l&1][l>>1][200]; B = EO
// direct-to-reg. ONE __syncthreads per block; latency hidden by ~4.8 w/SIMD.
// gridDim.x = 16 == 0 mod 8 => all m-blocks of a given x land on XCD x%8,
// so the 16-m-wide out lines accumulate in one L2 -> ~1x write amp.
__global__ __launch_bounds__(128) void stage2_kernel(const float* __restrict__ W,
                                                     const short* __restrict__ EO,
                                                     float* __restrict__ out,
                                                     int m0, int m_hi) {
    const int ltile = blockIdx.x;
    if (ltile >= 12) return;
    const int m = m0 + blockIdx.y;
    if (m >= m_hi) return;
    const int l0 = ltile * 32;
    if (l0 + 31 < m) return;                   // fully below diagonal

    __shared__ __align__(16) short Wl[2 * 16 * 200];   // 12.8 KB

    const int tid  = threadIdx.x;
    const int wav  = tid >> 6;
    const int lane = tid & 63;
    const int r    = lane & 15;
    const int kg   = (lane >> 4) * 8;          // shorts
    const int mloc = m - m0;

    // ---- W staging: 32 rows x 48 chunks(16B); thread p: row p>>2, c0 = p&3
    const int sl = tid >> 2;
    const int c0 = tid & 3;
    int lst = l0 + sl; if (lst > LMAX - 1) lst = LMAX - 1;   // ltile 11 dups, guarded below
    const float* wp = W + ((size_t)m * LMAX + lst) * NLAT;
    const int ldbase = ((sl & 1) * 16 + (sl >> 1)) * 200;
    f32x4 tv[12];
    #pragma unroll
    for (int j = 0; j < 12; ++j)
        tv[j] = *(const f32x4*)(wp + (c0 + 4 * j) * 4);

    // ---- B loads direct to registers (EO is L2/L3-resident)
    const short* be = EO + (((size_t)mloc * 2 + 0) * NJ + wav * 16 + r) * KFP + kg;
    const short* bo = EO + (((size_t)mloc * 2 + 1) * NJ + wav * 16 + r) * KFP + kg;
    bf16x8 Bfe[6], Bfo[6];
    #pragma unroll
    for (int t = 0; t < 6; ++t) {
        Bfe[t] = *(const bf16x8*)(be + t * 32);
        Bfo[t] = *(const bf16x8*)(bo + t * 32);
    }

    #pragma unroll
    for (int j = 0; j < 12; ++j) {
        bf16x4 h;
        #pragma unroll
        for (int e = 0; e < 4; ++e) h[e] = f2bf(tv[j][e]);
        *(bf16x4*)&Wl[ldbase + (c0 + 4 * j) * 4] = h;
    }
    __syncthreads();

    // ---- compute: E rows are l = m (mod 2)
    const int parE = m & 1;
    f32x4 accE = {0,0,0,0}, accO = {0,0,0,0};
    #pragma unroll
    for (int t = 0; t < 6; ++t) {
        bf16x8 aE = *(const bf16x8*)&Wl[(parE * 16 + r) * 200 + t * 32 + kg];
        bf16x8 aO = *(const bf16x8*)&Wl[((1 - parE) * 16 + r) * 200 + t * 32 + kg];
        accE = __builtin_amdgcn_mfma_f32_16x16x32_bf16(aE, Bfe[t], accE, 0, 0, 0);
        accO = __builtin_amdgcn_mfma_f32_16x16x32_bf16(aO, Bfo[t], accO, 0, 0, 0);
    }

    // ---- epilogue: col = bc (wav*16 + r), row lh -> l = l0 + par + 2*lh
    const int bc   = wav * 16 + r;
    const int rowg = (lane >> 4) * 4;
    #pragma unroll
    for (int i = 0; i < 4; ++i) {
        const int lh = rowg + i;
        const int le = l0 + parE + 2 * lh;
        const int lo = l0 + (1 - parE) + 2 * lh;
        if (le < LMAX) out[((size_t)bc * LMAX + le) * MMAX + m] = accE[i];
        if (lo < LMAX) out[((size_t)bc * LMAX + lo) * MMAX + m] = accO[i];
    }
}

extern "C" void kernel_launch(void* const* d_in, const int* in_sizes, int n_in,
                              void* d_out, int out_size, void* d_ws, size_t ws_size,
                              hipStream_t stream) {
    const float* x = (const float*)d_in[0];
    const float* w = (const float*)d_in[1];
    float* out = (float*)d_out;

    const size_t XR_OFF = (size_t)FT_ROWS_PAD * FT_COLS * 2;  // 565,248 B
    const size_t PER_M  = (size_t)2 * NJ * KFP * 2;           // 24,576 B per mode
    long cm = 0;
    if (d_ws != nullptr && ws_size > XR_OFF + PER_M) cm = (long)((ws_size - XR_OFF) / PER_M);
    if (cm > MMAX) cm = MMAX;
    if (cm < 1) return;

    short* FT = (short*)d_ws;
    short* EO = (short*)((char*)d_ws + XR_OFF);
    fill_ft_kernel<<<(FT_ROWS_PAD * FT_COLS + 255) / 256, 256, 0, stream>>>(FT);
    for (int m0 = 0; m0 < MMAX; m0 += (int)cm) {
        const int cmx = ((int)cm < MMAX - m0) ? (int)cm : (MMAX - m0);
        stage1_kernel<<<dim3(192), 512, 0, stream>>>(x, FT, EO, m0, cmx);
        stage2_kernel<<<dim3(16, cmx), 128, 0, stream>>>(w, EO, out, m0, m0 + cmx);
    }
}